// Round 1
// baseline (156.826 us; speedup 1.0000x reference)
//
#include <hip/hip_runtime.h>
#include <hip/hip_bf16.h>

// QuIP#-style quantized linear:
//   xh = fwht(x*SU)/sqrt(8192); W = cb[Qidxs]; z = xh @ W^T;
//   out = fwht(z)/sqrt(8192) * SV * Wscale
// Strategy: bf16 MFMA GEMM with on-the-fly codebook decompression.
// B-fragment of mfma_f32_16x16x32_bf16 = lane holds B[quad*8+j][lane&15]
// = 8 consecutive k of one output row = exactly one codebook entry.

typedef __attribute__((ext_vector_type(4))) float f32x4;
typedef __attribute__((ext_vector_type(8))) __bf16 bf16x8;
typedef __attribute__((ext_vector_type(4))) __bf16 bf16x4;

#define IN_F 8192
#define OUT_F 8192
#define TOKENS 32
#define KSPLIT 4
#define KCHUNK (IN_F / KSPLIT)       // 2048
#define NKT (KCHUNK / 32)            // 64 k-tiles of 32 per wave
#define INV_SQRT_8192 0.011048543456039806f

// ---------------- kernel 1: codebook fp32 -> bf16 ----------------
__global__ void cvt_cb_kernel(const float* __restrict__ cb,
                              __bf16* __restrict__ out) {
    int i = blockIdx.x * blockDim.x + threadIdx.x;   // 0..131071 (524288/4)
    const float4* in4 = (const float4*)cb;
    float4 v = in4[i];
    bf16x4 o;
    o[0] = (__bf16)v.x; o[1] = (__bf16)v.y;
    o[2] = (__bf16)v.z; o[3] = (__bf16)v.w;
    ((bf16x4*)out)[i] = o;
}

// ---------------- kernel 2: xh = fwht(x*SU)/sqrt(n) -> bf16 ----------------
__global__ void had_in_kernel(const float* __restrict__ x,
                              const float* __restrict__ su,
                              __bf16* __restrict__ xh) {
    __shared__ float s[IN_F];                         // 32 KB
    const int t = blockIdx.x;                         // token
    const int tid = threadIdx.x;                      // 0..1023
    #pragma unroll
    for (int i = tid; i < IN_F; i += 1024)
        s[i] = x[t * IN_F + i] * su[i];
    __syncthreads();
    for (int h = 1; h < IN_F; h <<= 1) {
        #pragma unroll
        for (int b = 0; b < 4; ++b) {
            int j = tid + b * 1024;                   // 0..4095 pair index
            int p = ((j & ~(h - 1)) << 1) | (j & (h - 1));
            float a = s[p], c = s[p + h];
            s[p] = a + c;
            s[p + h] = a - c;
        }
        __syncthreads();
    }
    #pragma unroll
    for (int i = tid; i < IN_F; i += 1024)
        xh[t * IN_F + i] = (__bf16)(s[i] * INV_SQRT_8192);
}

// ---------------- kernel 3: z = xh @ W^T with on-the-fly decompress --------
__global__ __launch_bounds__(256, 2)
void qgemm_kernel(const int* __restrict__ qidxs,
                  const __bf16* __restrict__ cb,
                  const __bf16* __restrict__ xh,
                  float* __restrict__ zpart) {
    const int ks   = blockIdx.x & (KSPLIT - 1);
    const int nb   = blockIdx.x >> 2;                 // 0..127
    const int wave = threadIdx.x >> 6;                // 0..3
    const int lane = threadIdx.x & 63;
    const int quad = lane >> 4;                       // 0..3
    const int l16  = lane & 15;
    const int n = nb * 64 + wave * 16 + l16;          // output feature

    const int* qrow = qidxs + n * (IN_F / 8) + ks * (KCHUNK / 8);
    const bf16x8* a0p = (const bf16x8*)(xh + l16 * IN_F + ks * KCHUNK + quad * 8);
    const bf16x8* a1p = (const bf16x8*)(xh + (l16 + 16) * IN_F + ks * KCHUNK + quad * 8);
    const bf16x8* cbv = (const bf16x8*)cb;

    f32x4 acc0 = {0.f, 0.f, 0.f, 0.f};
    f32x4 acc1 = {0.f, 0.f, 0.f, 0.f};

    #pragma unroll 4
    for (int kt = 0; kt < NKT; ++kt) {
        int idx = qrow[kt * 4 + quad];                // 1 int per lane
        bf16x8 b = cbv[idx];                          // 16 B gather = B frag
        bf16x8 a0 = a0p[kt * 4];                      // xh[l16][k0..k0+7 per quad]
        bf16x8 a1 = a1p[kt * 4];
        acc0 = __builtin_amdgcn_mfma_f32_16x16x32_bf16(a0, b, acc0, 0, 0, 0);
        acc1 = __builtin_amdgcn_mfma_f32_16x16x32_bf16(a1, b, acc1, 0, 0, 0);
    }

    // D layout: D[m=quad*4+r][n=l16]
    float* zp = zpart + (size_t)ks * TOKENS * OUT_F + n;
    #pragma unroll
    for (int r = 0; r < 4; ++r) {
        zp[(quad * 4 + r) * OUT_F] = acc0[r];
        zp[(16 + quad * 4 + r) * OUT_F] = acc1[r];
    }
}

// ---------------- kernel 4: out = fwht(sum zpart)/sqrt(n) * SV * Wscale ----
__global__ void had_out_kernel(const float* __restrict__ zpart,
                               const float* __restrict__ sv,
                               const float* __restrict__ wscale,
                               float* __restrict__ out) {
    __shared__ float s[OUT_F];                        // 32 KB
    const int t = blockIdx.x;
    const int tid = threadIdx.x;
    #pragma unroll
    for (int i = tid; i < OUT_F; i += 1024) {
        float acc = 0.f;
        #pragma unroll
        for (int ks = 0; ks < KSPLIT; ++ks)
            acc += zpart[((size_t)ks * TOKENS + t) * OUT_F + i];
        s[i] = acc;
    }
    __syncthreads();
    for (int h = 1; h < OUT_F; h <<= 1) {
        #pragma unroll
        for (int b = 0; b < 4; ++b) {
            int j = tid + b * 1024;
            int p = ((j & ~(h - 1)) << 1) | (j & (h - 1));
            float a = s[p], c = s[p + h];
            s[p] = a + c;
            s[p + h] = a - c;
        }
        __syncthreads();
    }
    const float sc = INV_SQRT_8192 * wscale[0];
    #pragma unroll
    for (int i = tid; i < OUT_F; i += 1024)
        out[t * OUT_F + i] = s[i] * sc * sv[i];
}

extern "C" void kernel_launch(void* const* d_in, const int* in_sizes, int n_in,
                              void* d_out, int out_size, void* d_ws, size_t ws_size,
                              hipStream_t stream) {
    const float* x      = (const float*)d_in[0];   // (32, 8192)
    const float* cb     = (const float*)d_in[1];   // (65536, 8)
    const int*   qidxs  = (const int*)d_in[2];     // (8192, 1024)
    const float* su     = (const float*)d_in[3];   // (8192,)
    const float* sv     = (const float*)d_in[4];   // (8192,)
    const float* wscale = (const float*)d_in[5];   // scalar
    float* out = (float*)d_out;                    // (32, 8192) fp32

    char* ws = (char*)d_ws;
    __bf16* cb_bf16 = (__bf16*)ws;                               // 1 MB
    __bf16* xh      = (__bf16*)(ws + (1u << 20));                // 512 KB
    float*  zpart   = (float*)(ws + (1u << 20) + (512u << 10));  // 4 MB

    hipLaunchKernelGGL(cvt_cb_kernel, dim3(512), dim3(256), 0, stream,
                       cb, cb_bf16);
    hipLaunchKernelGGL(had_in_kernel, dim3(TOKENS), dim3(1024), 0, stream,
                       x, su, xh);
    hipLaunchKernelGGL(qgemm_kernel, dim3(128 * KSPLIT), dim3(256), 0, stream,
                       qidxs, cb_bf16, xh, zpart);
    hipLaunchKernelGGL(had_out_kernel, dim3(TOKENS), dim3(1024), 0, stream,
                       zpart, sv, wscale, out);
}